// Round 1
// baseline (66.805 us; speedup 1.0000x reference)
//
#include <hip/hip_runtime.h>

// DifferentiableCBFLayer: batched HOCBF-QP via ADMM (100 iters), 1 thread = 1 batch elem.
// State reduction: (z,y) -> w, where w = v + y_old (rho=1);
//   t = rho*z - y = (w<=b ? w : 2b-w);  w_new = v_new + max(w_old - b, 0); w0 = min(0,b).

constexpr int NOBS = 16;
constexpr int NAG  = 8;
constexpr int NITERS = 100;

__global__ __launch_bounds__(256, 1)
void cbf_admm_kernel(const float* __restrict__ u_nom,   // (B,2)
                     const float* __restrict__ v_cur,   // (B,1)
                     const float* __restrict__ p_obs,   // (B,16,2)
                     const float* __restrict__ p_ag,    // (B,8,2)
                     const float* __restrict__ v_ag,    // (B,8,2)
                     const float* __restrict__ ag_act,  // (B,8)
                     const float* __restrict__ ob_act,  // (B,16)
                     float* __restrict__ out,           // (B,2)
                     int B)
{
    const int b = blockIdx.x * blockDim.x + threadIdx.x;
    if (b >= B) return;

    const float v   = v_cur[b];
    const float2 un = *reinterpret_cast<const float2*>(u_nom + 2 * (size_t)b);
    const float ur0 = un.x * 1.0f;   // A_MAX = 1
    const float ur1 = un.y * 1.0f;   // W_MAX = 1

    // ---------------- build obstacle rows ----------------
    float ga_o[NOBS], gw_o[NOBS], h_o[NOBS];
    {
        const float4* po = reinterpret_cast<const float4*>(p_obs + (size_t)b * 2 * NOBS);
        const float4* oa = reinterpret_cast<const float4*>(ob_act + (size_t)b * NOBS);
        #pragma unroll
        for (int q = 0; q < NOBS / 4; ++q) {        // 4 obstacles per step
            float4 a = po[2 * q], c = po[2 * q + 1];
            float4 act = oa[q];
            float lx[4]  = {a.x, a.z, c.x, c.z};
            float ly[4]  = {a.y, a.w, c.y, c.w};
            float av[4]  = {act.x, act.y, act.z, act.w};
            #pragma unroll
            for (int r = 0; r < 4; ++r) {
                const int i = 4 * q + r;
                const float X = lx[r], Y = ly[r];
                ga_o[i] = 2.f * X;
                gw_o[i] = 2.f * Y * v;
                const float h_obs = X * X + Y * Y - 0.25f;       // D_OBS^2
                const float hdot  = -2.f * X * v;
                h_o[i] = (2.f * v * v + 2.f * hdot + h_obs) * av[r];  // DAMPING=2, STIFF=1
            }
        }
    }

    // ---------------- build agent rows (avoid + conn share +/-A) ----------------
    float gaa[NAG], gwa[NAG], h_av[NAG], h_cn[NAG];
    {
        const float4* pa  = reinterpret_cast<const float4*>(p_ag  + (size_t)b * 2 * NAG);
        const float4* va  = reinterpret_cast<const float4*>(v_ag  + (size_t)b * 2 * NAG);
        const float4* aa4 = reinterpret_cast<const float4*>(ag_act + (size_t)b * NAG);
        float4 A0 = aa4[0], A1 = aa4[1];
        float actv[NAG] = {A0.x, A0.y, A0.z, A0.w, A1.x, A1.y, A1.z, A1.w};
        #pragma unroll
        for (int q = 0; q < NAG / 2; ++q) {         // 2 agents per step
            float4 p  = pa[q];
            float4 w4 = va[q];
            float lxs[2]  = {p.x,  p.z},  lys[2]  = {p.y,  p.w};
            float vjxs[2] = {w4.x, w4.z}, vjys[2] = {w4.y, w4.w};
            #pragma unroll
            for (int r = 0; r < 2; ++r) {
                const int j = 2 * q + r;
                const float X = lxs[r], Y = lys[r];
                const float VX = vjxs[r], VY = vjys[r];
                const float act = actv[j];
                const float d2 = X * X + Y * Y;
                const float h_avoid = d2 - 0.25f;                 // D_SAFE^2
                const float hdot  = -2.f * X * v + 2.f * (X * VX + Y * VY);
                const float hddc  = 2.f * v * v - 4.f * v * VX + 2.f * VX * VX + 2.f * VY * VY;
                const float Ga = 2.f * X;
                const float Gw = 2.f * Y * v - 2.f * Y * VX + 2.f * X * VY;
                gaa[j]  = Ga * act;
                gwa[j]  = Gw * act;
                h_av[j] = (hddc + 2.f * hdot + h_avoid) * act;
                h_cn[j] = (-hddc - 2.f * hdot + (100.f - d2)) * act;  // D_MAX^2=100
            }
        }
    }

    // ---------------- M = Q + A^T A  (symmetric 3x3), closed-form inverse ----------------
    float M00 = 4.f, M01 = 0.f, M11 = 4.f, M02 = 0.f, M12 = 0.f;  // Q(2,2)+box(2,2)
    const float M22 = 217.f;   // 2*W_SLACK + 16 obs rows (-1)^2 + box slack row
    #pragma unroll
    for (int i = 0; i < NOBS; ++i) {
        M00 += ga_o[i] * ga_o[i];
        M01 += ga_o[i] * gw_o[i];
        M11 += gw_o[i] * gw_o[i];
        M02 -= ga_o[i];
        M12 -= gw_o[i];
    }
    #pragma unroll
    for (int j = 0; j < NAG; ++j) {   // avoid + conn rows contribute twice
        M00 += 2.f * gaa[j] * gaa[j];
        M01 += 2.f * gaa[j] * gwa[j];
        M11 += 2.f * gwa[j] * gwa[j];
    }
    const float c00 = M11 * M22 - M12 * M12;
    const float c01 = M02 * M12 - M01 * M22;
    const float c02 = M01 * M12 - M02 * M11;
    const float det = M00 * c00 + M01 * c01 + M02 * c02;
    const float id  = 1.f / det;
    const float i00 = c00 * id, i01 = c01 * id, i02 = c02 * id;
    const float i11 = (M00 * M22 - M02 * M02) * id;
    const float i12 = (M01 * M02 - M00 * M12) * id;
    const float i22 = (M00 * M11 - M01 * M01) * id;

    // ---------------- ADMM state: w per constraint, w0 = min(0, b) ----------------
    float w_o[NOBS], w_av[NAG], w_cn[NAG];
    #pragma unroll
    for (int i = 0; i < NOBS; ++i) w_o[i] = fminf(0.f, h_o[i]);
    #pragma unroll
    for (int j = 0; j < NAG; ++j) { w_av[j] = fminf(0.f, h_av[j]); w_cn[j] = fminf(0.f, h_cn[j]); }
    float wb0 = 0.f, wb1 = 0.f, wb2 = 0.f, wb3 = 0.f, wb4 = 0.f;  // box b = {1,1,1,1,0}

    float x0 = 0.f, x1 = 0.f, x2 = 0.f;

    #pragma unroll 1
    for (int it = 0; it < NITERS; ++it) {
        // t_k = (w<=b ? w : 2b-w);  r = -q + A^T t
        float r0 = 2.f * ur0, r1 = 2.f * ur1, r2 = 0.f;
        #pragma unroll
        for (int i = 0; i < NOBS; ++i) {
            const float wv = w_o[i], bb = h_o[i];
            const float t = (wv <= bb) ? wv : (2.f * bb - wv);
            r0 += ga_o[i] * t;
            r1 += gw_o[i] * t;
            r2 -= t;
        }
        #pragma unroll
        for (int j = 0; j < NAG; ++j) {
            const float wa = w_av[j], ba = h_av[j];
            const float ta = (wa <= ba) ? wa : (2.f * ba - wa);
            const float wc = w_cn[j], bc = h_cn[j];
            const float tc = (wc <= bc) ? wc : (2.f * bc - wc);
            const float td = ta - tc;           // conn row = -avoid row
            r0 += gaa[j] * td;
            r1 += gwa[j] * td;
        }
        {   // box rows
            const float t0 = (wb0 <= 1.f) ? wb0 : (2.f - wb0);
            const float t1 = (wb1 <= 1.f) ? wb1 : (2.f - wb1);
            const float t2 = (wb2 <= 1.f) ? wb2 : (2.f - wb2);
            const float t3 = (wb3 <= 1.f) ? wb3 : (2.f - wb3);
            const float t4 = (wb4 <= 0.f) ? wb4 : (-wb4);
            r0 += t1 - t0;
            r1 += t3 - t2;
            r2 -= t4;
        }
        // x = Minv * r
        x0 = i00 * r0 + i01 * r1 + i02 * r2;
        x1 = i01 * r0 + i11 * r1 + i12 * r2;
        x2 = i02 * r0 + i12 * r1 + i22 * r2;
        // v = A x ;  w_new = v + max(w_old - b, 0)
        #pragma unroll
        for (int i = 0; i < NOBS; ++i) {
            const float vv = ga_o[i] * x0 + gw_o[i] * x1 - x2;
            w_o[i] = vv + fmaxf(w_o[i] - h_o[i], 0.f);
        }
        #pragma unroll
        for (int j = 0; j < NAG; ++j) {
            const float va = gaa[j] * x0 + gwa[j] * x1;
            w_av[j] =  va + fmaxf(w_av[j] - h_av[j], 0.f);
            w_cn[j] = -va + fmaxf(w_cn[j] - h_cn[j], 0.f);
        }
        wb0 = -x0 + fmaxf(wb0 - 1.f, 0.f);
        wb1 =  x0 + fmaxf(wb1 - 1.f, 0.f);
        wb2 = -x1 + fmaxf(wb2 - 1.f, 0.f);
        wb3 =  x1 + fmaxf(wb3 - 1.f, 0.f);
        wb4 = -x2 + fmaxf(wb4, 0.f);
    }

    // u_safe = x[:2] / action_scale (scale = 1)
    reinterpret_cast<float2*>(out)[b] = make_float2(x0, x1);
}

extern "C" void kernel_launch(void* const* d_in, const int* in_sizes, int n_in,
                              void* d_out, int out_size, void* d_ws, size_t ws_size,
                              hipStream_t stream) {
    const float* u_nom  = (const float*)d_in[0];
    const float* v_cur  = (const float*)d_in[1];
    const float* p_obs  = (const float*)d_in[2];
    const float* p_ag   = (const float*)d_in[3];
    const float* v_ag   = (const float*)d_in[4];
    const float* ag_act = (const float*)d_in[5];
    const float* ob_act = (const float*)d_in[6];
    float* out = (float*)d_out;

    const int B = in_sizes[1];            // v_current is (B,1)
    dim3 block(256), grid((B + 255) / 256);
    hipLaunchKernelGGL(cbf_admm_kernel, grid, block, 0, stream,
                       u_nom, v_cur, p_obs, p_ag, v_ag, ag_act, ob_act, out, B);
}

// Round 2
// 49.667 us; speedup vs baseline: 1.3451x; 1.3451x over previous
//
#include <hip/hip_runtime.h>

// DifferentiableCBFLayer: batched HOCBF-QP via ADMM (100 iters), 1 thread = 1 batch elem.
// State reduction: (z,y) -> w (rho=1):
//   t = rho*z - y = b - |w - b|          (replaces cmp/select)
//   w_new = v_new + max(w_old - b, 0);   w0 = min(0,b)
// All constraint arrays packed as float2 -> v_pk_{fma,add,max}_f32.

constexpr int NOBS = 16;
constexpr int NAG  = 8;
constexpr int NITERS = 100;

typedef float v2 __attribute__((ext_vector_type(2)));

static __device__ __forceinline__ v2 vfma(v2 a, v2 b, v2 c) { return __builtin_elementwise_fma(a, b, c); }
static __device__ __forceinline__ v2 vmax(v2 a, v2 b)       { return __builtin_elementwise_max(a, b); }
static __device__ __forceinline__ v2 vabs(v2 a)             { return __builtin_elementwise_abs(a); }

__global__ __launch_bounds__(256, 1)
void cbf_admm_kernel(const float* __restrict__ u_nom,   // (B,2)
                     const float* __restrict__ v_cur,   // (B,1)
                     const float* __restrict__ p_obs,   // (B,16,2)
                     const float* __restrict__ p_ag,    // (B,8,2)
                     const float* __restrict__ v_ag,    // (B,8,2)
                     const float* __restrict__ ag_act,  // (B,8)
                     const float* __restrict__ ob_act,  // (B,16)
                     float* __restrict__ out,           // (B,2)
                     int B)
{
    const int b = blockIdx.x * blockDim.x + threadIdx.x;
    if (b >= B) return;

    const float v   = v_cur[b];
    const float2 un = *reinterpret_cast<const float2*>(u_nom + 2 * (size_t)b);
    const float ur0 = un.x;   // A_MAX = 1
    const float ur1 = un.y;   // W_MAX = 1

    // ---------------- build obstacle rows (packed: 2 obstacles per v2) ----------------
    v2 ga2[8], gw2[8], h2[8];
    {
        const float4* po = reinterpret_cast<const float4*>(p_obs + (size_t)b * 2 * NOBS);
        const float2* oa = reinterpret_cast<const float2*>(ob_act + (size_t)b * NOBS);
        #pragma unroll
        for (int q = 0; q < 8; ++q) {               // pair q = obstacles 2q, 2q+1
            const float4 p  = po[q];                // lx0, ly0, lx1, ly1
            const float2 ac = oa[q];
            const v2 lx = {p.x, p.z};
            const v2 ly = {p.y, p.w};
            const v2 act = {ac.x, ac.y};
            ga2[q] = 2.f * lx;
            gw2[q] = (2.f * v) * ly;
            const v2 h_obs = lx * lx + ly * ly - 0.25f;          // D_OBS^2
            const v2 hdot  = (-2.f * v) * lx;
            h2[q] = (2.f * v * v + 2.f * hdot + h_obs) * act;    // DAMPING=2, STIFF=1
        }
    }

    // ---------------- build agent rows (packed: 2 agents per v2) ----------------
    v2 gaa2[4], gwa2[4], hav2[4], hcn2[4];
    {
        const float4* pa  = reinterpret_cast<const float4*>(p_ag  + (size_t)b * 2 * NAG);
        const float4* va  = reinterpret_cast<const float4*>(v_ag  + (size_t)b * 2 * NAG);
        const float2* aa  = reinterpret_cast<const float2*>(ag_act + (size_t)b * NAG);
        #pragma unroll
        for (int q = 0; q < 4; ++q) {               // pair q = agents 2q, 2q+1
            const float4 p  = pa[q];
            const float4 w4 = va[q];
            const float2 ac = aa[q];
            const v2 lx = {p.x,  p.z},  ly = {p.y,  p.w};
            const v2 vx = {w4.x, w4.z}, vy = {w4.y, w4.w};
            const v2 act = {ac.x, ac.y};
            const v2 d2  = lx * lx + ly * ly;
            const v2 h_avoid = d2 - 0.25f;                        // D_SAFE^2
            const v2 hdot = (-2.f * v) * lx + 2.f * (lx * vx + ly * vy);
            const v2 hddc = (2.f * v * v) + (-4.f * v) * vx + 2.f * (vx * vx + vy * vy);
            const v2 Ga = 2.f * lx;
            const v2 Gw = (2.f * v) * ly - 2.f * ly * vx + 2.f * lx * vy;
            gaa2[q] = Ga * act;
            gwa2[q] = Gw * act;
            hav2[q] = (hddc + 2.f * hdot + h_avoid) * act;
            hcn2[q] = (-hddc - 2.f * hdot + (100.f - d2)) * act;  // D_MAX^2 = 100
        }
    }

    // ---------------- M = Q + A^T A (symmetric 3x3), closed-form inverse ----------------
    v2 m00 = {4.f, 0.f}, m01 = {0.f, 0.f}, m11 = {4.f, 0.f}, m02 = {0.f, 0.f}, m12 = {0.f, 0.f};
    #pragma unroll
    for (int q = 0; q < 8; ++q) {
        m00 = vfma(ga2[q], ga2[q], m00);
        m01 = vfma(ga2[q], gw2[q], m01);
        m11 = vfma(gw2[q], gw2[q], m11);
        m02 = m02 - ga2[q];
        m12 = m12 - gw2[q];
    }
    #pragma unroll
    for (int q = 0; q < 4; ++q) {   // avoid + conn contribute twice
        const v2 two = {2.f, 2.f};
        m00 = vfma(two * gaa2[q], gaa2[q], m00);
        m01 = vfma(two * gaa2[q], gwa2[q], m01);
        m11 = vfma(two * gwa2[q], gwa2[q], m11);
    }
    const float M00 = m00.x + m00.y, M01 = m01.x + m01.y, M11 = m11.x + m11.y;
    const float M02 = m02.x + m02.y, M12 = m12.x + m12.y;
    const float M22 = 217.f;   // 2*W_SLACK + 16 obs rows + box slack row
    const float c00 = M11 * M22 - M12 * M12;
    const float c01 = M02 * M12 - M01 * M22;
    const float c02 = M01 * M12 - M02 * M11;
    const float det = M00 * c00 + M01 * c01 + M02 * c02;
    const float id  = 1.f / det;
    const float i00 = c00 * id, i01 = c01 * id, i02 = c02 * id;
    const float i11 = (M00 * M22 - M02 * M02) * id;
    const float i12 = (M01 * M02 - M00 * M12) * id;
    const float i22 = (M00 * M11 - M01 * M01) * id;

    // ---------------- ADMM state: w = min(0, b) per constraint ----------------
    const v2 Z = {0.f, 0.f};
    v2 w2[8], wav2[4], wcn2[4];
    #pragma unroll
    for (int q = 0; q < 8; ++q) w2[q] = __builtin_elementwise_min(Z, h2[q]);
    #pragma unroll
    for (int q = 0; q < 4; ++q) {
        wav2[q] = __builtin_elementwise_min(Z, hav2[q]);
        wcn2[q] = __builtin_elementwise_min(Z, hcn2[q]);
    }
    v2 wb01 = Z, wb23 = Z;           // box rows (-x0<=1, x0<=1), (-x1<=1, x1<=1)
    float wb4 = 0.f;                 // box row -x2 <= 0
    const v2 ONE = {1.f, 1.f};

    float x0 = 0.f, x1 = 0.f, x2 = 0.f;

    #pragma unroll 1
    for (int it = 0; it < NITERS; ++it) {
        // ---- t = b - |w-b|;  r = -q + A^T t ----
        v2 a0 = Z, a1 = Z, a2 = Z;
        v2 dobs[8], dav[4], dcn[4];
        #pragma unroll
        for (int q = 0; q < 8; ++q) {
            const v2 d = w2[q] - h2[q];
            dobs[q] = d;
            const v2 t = h2[q] - vabs(d);
            a0 = vfma(ga2[q], t, a0);
            a1 = vfma(gw2[q], t, a1);
            a2 = a2 - t;                       // third column = -1 for obs rows
        }
        #pragma unroll
        for (int q = 0; q < 4; ++q) {
            const v2 da = wav2[q] - hav2[q];  dav[q] = da;
            const v2 dc = wcn2[q] - hcn2[q];  dcn[q] = dc;
            const v2 ta = hav2[q] - vabs(da);
            const v2 tc = hcn2[q] - vabs(dc);
            const v2 td = ta - tc;            // conn row = -avoid row
            a0 = vfma(gaa2[q], td, a0);
            a1 = vfma(gwa2[q], td, a1);
        }
        const v2 db01 = wb01 - ONE, db23 = wb23 - ONE;
        const v2 tb01 = ONE - vabs(db01), tb23 = ONE - vabs(db23);
        const float tb4 = -fabsf(wb4);

        const float r0 = 2.f * ur0 + a0.x + a0.y + (tb01.y - tb01.x);
        const float r1 = 2.f * ur1 + a1.x + a1.y + (tb23.y - tb23.x);
        const float r2 = a2.x + a2.y - tb4;

        // ---- x = Minv r ----
        x0 = fmaf(i00, r0, fmaf(i01, r1, i02 * r2));
        x1 = fmaf(i01, r0, fmaf(i11, r1, i12 * r2));
        x2 = fmaf(i02, r0, fmaf(i12, r1, i22 * r2));

        // ---- v = A x ; w' = v + max(d, 0) ----
        const v2 X0 = {x0, x0}, X1 = {x1, x1}, NX2 = {-x2, -x2};
        #pragma unroll
        for (int q = 0; q < 8; ++q) {
            const v2 vv = vfma(ga2[q], X0, vfma(gw2[q], X1, NX2));
            w2[q] = vv + vmax(dobs[q], Z);
        }
        #pragma unroll
        for (int q = 0; q < 4; ++q) {
            const v2 va = vfma(gaa2[q], X0, gwa2[q] * X1);
            wav2[q] = va + vmax(dav[q], Z);
            wcn2[q] = vmax(dcn[q], Z) - va;
        }
        const v2 sx0 = {-x0, x0}, sx1 = {-x1, x1};
        wb01 = sx0 + vmax(db01, Z);
        wb23 = sx1 + vmax(db23, Z);
        wb4  = -x2 + fmaxf(wb4, 0.f);
    }

    reinterpret_cast<float2*>(out)[b] = make_float2(x0, x1);
}

extern "C" void kernel_launch(void* const* d_in, const int* in_sizes, int n_in,
                              void* d_out, int out_size, void* d_ws, size_t ws_size,
                              hipStream_t stream) {
    const float* u_nom  = (const float*)d_in[0];
    const float* v_cur  = (const float*)d_in[1];
    const float* p_obs  = (const float*)d_in[2];
    const float* p_ag   = (const float*)d_in[3];
    const float* v_ag   = (const float*)d_in[4];
    const float* ag_act = (const float*)d_in[5];
    const float* ob_act = (const float*)d_in[6];
    float* out = (float*)d_out;

    const int B = in_sizes[1];            // v_current is (B,1)
    dim3 block(256), grid((B + 255) / 256);
    hipLaunchKernelGGL(cbf_admm_kernel, grid, block, 0, stream,
                       u_nom, v_cur, p_obs, p_ag, v_ag, ag_act, ob_act, out, B);
}

// Round 3
// 49.522 us; speedup vs baseline: 1.3490x; 1.0029x over previous
//
#include <hip/hip_runtime.h>

// DifferentiableCBFLayer: batched HOCBF-QP via ADMM (100 iters).
// TWO lanes per batch element (lane pair 2e, 2e+1): each lane owns half the
// constraint rows; per-iter cross-lane reduce of A^T t via DPP quad_perm swap.
// State reduction (rho=1): t = b - |w-b| ;  w' = A x + max(w-b, 0) ; w0 = min(0,b).

constexpr int NITERS = 100;

typedef float v2 __attribute__((ext_vector_type(2)));

static __device__ __forceinline__ v2 vfma(v2 a, v2 b, v2 c) { return __builtin_elementwise_fma(a, b, c); }
static __device__ __forceinline__ v2 vmax(v2 a, v2 b)       { return __builtin_elementwise_max(a, b); }
static __device__ __forceinline__ v2 vmin(v2 a, v2 b)       { return __builtin_elementwise_min(a, b); }
static __device__ __forceinline__ v2 vabs(v2 a)             { return __builtin_elementwise_abs(a); }

// lane 2k <-> 2k+1 swap, pure-VALU DPP (quad_perm [1,0,3,2])
static __device__ __forceinline__ float lane_swap(float x) {
    return __int_as_float(__builtin_amdgcn_mov_dpp(__float_as_int(x), 0xB1, 0xF, 0xF, true));
}

__global__ __launch_bounds__(256, 2)
void cbf_admm_kernel(const float* __restrict__ u_nom,   // (B,2)
                     const float* __restrict__ v_cur,   // (B,1)
                     const float* __restrict__ p_obs,   // (B,16,2)
                     const float* __restrict__ p_ag,    // (B,8,2)
                     const float* __restrict__ v_ag,    // (B,8,2)
                     const float* __restrict__ ag_act,  // (B,8)
                     const float* __restrict__ ob_act,  // (B,16)
                     float* __restrict__ out,           // (B,2)
                     int B)
{
    const int t  = blockIdx.x * blockDim.x + threadIdx.x;
    const int e  = t >> 1;        // batch element
    const int hf = t & 1;         // which half of the constraints this lane owns
    if (e >= B) return;

    const float v   = v_cur[e];
    const float2 un = *reinterpret_cast<const float2*>(u_nom + 2 * (size_t)e);
    const float ur0 = un.x;       // A_MAX = 1
    const float ur1 = un.y;       // W_MAX = 1

    // ---------------- this lane's 8 obstacles (4 packed pairs) ----------------
    v2 ga2[4], gw2[4], h2[4];
    {
        const float4* po = reinterpret_cast<const float4*>(p_obs) + 4 * (size_t)t;  // e*8 + hf*4
        const float4* oa = reinterpret_cast<const float4*>(ob_act) + 2 * (size_t)t; // e*4 + hf*2
        const float4 A0 = oa[0], A1 = oa[1];
        const float oaf[8] = {A0.x, A0.y, A0.z, A0.w, A1.x, A1.y, A1.z, A1.w};
        #pragma unroll
        for (int q = 0; q < 4; ++q) {
            const float4 p = po[q];                 // lx0, ly0, lx1, ly1
            const v2 lx = {p.x, p.z};
            const v2 ly = {p.y, p.w};
            const v2 act = {oaf[2 * q], oaf[2 * q + 1]};
            ga2[q] = 2.f * lx;
            gw2[q] = (2.f * v) * ly;
            const v2 h_obs = lx * lx + ly * ly - 0.25f;          // D_OBS^2
            const v2 hdot  = (-2.f * v) * lx;
            h2[q] = (2.f * v * v + 2.f * hdot + h_obs) * act;    // DAMPING=2, STIFF=1
        }
    }

    // ---------------- this lane's 4 agents (2 packed pairs) ----------------
    v2 gaa2[2], gwa2[2], hav2[2], hcn2[2];
    {
        const float4* pa = reinterpret_cast<const float4*>(p_ag) + 2 * (size_t)t;   // e*4 + hf*2
        const float4* va = reinterpret_cast<const float4*>(v_ag) + 2 * (size_t)t;
        const float4 AA  = reinterpret_cast<const float4*>(ag_act)[t];              // e*2 + hf
        const float aaf[4] = {AA.x, AA.y, AA.z, AA.w};
        #pragma unroll
        for (int q = 0; q < 2; ++q) {
            const float4 p  = pa[q];
            const float4 w4 = va[q];
            const v2 lx = {p.x,  p.z},  ly = {p.y,  p.w};
            const v2 vx = {w4.x, w4.z}, vy = {w4.y, w4.w};
            const v2 act = {aaf[2 * q], aaf[2 * q + 1]};
            const v2 d2  = lx * lx + ly * ly;
            const v2 h_avoid = d2 - 0.25f;                        // D_SAFE^2
            const v2 hdot = (-2.f * v) * lx + 2.f * (lx * vx + ly * vy);
            const v2 hddc = (2.f * v * v) + (-4.f * v) * vx + 2.f * (vx * vx + vy * vy);
            const v2 Ga = 2.f * lx;
            const v2 Gw = (2.f * v) * ly - 2.f * ly * vx + 2.f * lx * vy;
            gaa2[q] = Ga * act;
            gwa2[q] = Gw * act;
            hav2[q] = (hddc + 2.f * hdot + h_avoid) * act;
            hcn2[q] = (-hddc - 2.f * hdot + (100.f - d2)) * act;  // D_MAX^2 = 100
        }
    }

    // ---------------- M = Q + A^T A partials, cross-lane reduce, invert ----------------
    v2 m00 = {0.f, 0.f}, m01 = m00, m11 = m00, m02 = m00, m12 = m00;
    #pragma unroll
    for (int q = 0; q < 4; ++q) {
        m00 = vfma(ga2[q], ga2[q], m00);
        m01 = vfma(ga2[q], gw2[q], m01);
        m11 = vfma(gw2[q], gw2[q], m11);
        m02 = m02 - ga2[q];
        m12 = m12 - gw2[q];
    }
    #pragma unroll
    for (int q = 0; q < 2; ++q) {   // avoid + conn rows contribute twice
        const v2 g2 = gaa2[q] + gaa2[q];
        m00 = vfma(g2, gaa2[q], m00);
        m01 = vfma(g2, gwa2[q], m01);
        m11 = vfma(gwa2[q] + gwa2[q], gwa2[q], m11);
    }
    float pM00 = m00.x + m00.y, pM01 = m01.x + m01.y, pM11 = m11.x + m11.y;
    float pM02 = m02.x + m02.y, pM12 = m12.x + m12.y;
    const float M00 = pM00 + lane_swap(pM00) + 4.f;   // Q(2) + box x0 rows(2)
    const float M01 = pM01 + lane_swap(pM01);
    const float M11 = pM11 + lane_swap(pM11) + 4.f;   // Q(2) + box x1 rows(2)
    const float M02 = pM02 + lane_swap(pM02);
    const float M12 = pM12 + lane_swap(pM12);
    const float M22 = 217.f;   // 2*W_SLACK + 16 obs rows + box slack row
    const float c00 = M11 * M22 - M12 * M12;
    const float c01 = M02 * M12 - M01 * M22;
    const float c02 = M01 * M12 - M02 * M11;
    const float det = M00 * c00 + M01 * c01 + M02 * c02;
    const float id  = 1.f / det;
    const float i00 = c00 * id, i01 = c01 * id, i02 = c02 * id;
    const float i11 = (M00 * M22 - M02 * M02) * id;
    const float i12 = (M01 * M02 - M00 * M12) * id;
    const float i22 = (M00 * M11 - M01 * M01) * id;

    // ---------------- ADMM state: w = min(0, b) ----------------
    const v2 Z = {0.f, 0.f};
    const v2 ONE = {1.f, 1.f};
    v2 w2[4], wav2[2], wcn2[2];
    #pragma unroll
    for (int q = 0; q < 4; ++q) w2[q] = vmin(Z, h2[q]);
    #pragma unroll
    for (int q = 0; q < 2; ++q) {
        wav2[q] = vmin(Z, hav2[q]);
        wcn2[q] = vmin(Z, hcn2[q]);
    }
    v2 wbp = Z;            // lane0: (-x0<=1, x0<=1) ; lane1: (-x1<=1, x1<=1)
    float wb4 = 0.f;       // slack row -x2 <= 0 (state kept on both lanes; only lane0 contributes)

    float x0 = 0.f, x1 = 0.f, x2 = 0.f;

    #pragma unroll 1
    for (int it = 0; it < NITERS; ++it) {
        // ---- t = b - |w-b| ; partial A^T t ----
        v2 a0 = Z, a1 = Z, tsum = Z;
        v2 dobs[4], dav[2], dcn[2];
        #pragma unroll
        for (int q = 0; q < 4; ++q) {
            const v2 d = w2[q] - h2[q];
            dobs[q] = d;
            const v2 tt = h2[q] - vabs(d);
            a0 = vfma(ga2[q], tt, a0);
            a1 = vfma(gw2[q], tt, a1);
            tsum = tsum + tt;                     // obs third column = -1
        }
        #pragma unroll
        for (int q = 0; q < 2; ++q) {
            const v2 da = wav2[q] - hav2[q];  dav[q] = da;
            const v2 dc = wcn2[q] - hcn2[q];  dcn[q] = dc;
            const v2 ta = hav2[q] - vabs(da);
            const v2 tc = hcn2[q] - vabs(dc);
            const v2 td = ta - tc;                // conn row = -avoid row
            a0 = vfma(gaa2[q], td, a0);
            a1 = vfma(gwa2[q], td, a1);
        }
        // box pair (this lane's variable), slack row (lane0 only)
        const v2 db = wbp - ONE;
        const v2 tb = ONE - vabs(db);
        const float rbox = tb.y - tb.x;

        float p0 = a0.x + a0.y;
        float p1 = a1.x + a1.y;
        float p2 = -(tsum.x + tsum.y);
        p0 += hf ? 0.f : rbox;
        p1 += hf ? rbox : 0.f;
        p2 += hf ? 0.f : fabsf(wb4);              // t4 = -|wb4| ; r2 -= t4

        // ---- cross-lane reduce (identical fp result on both lanes) ----
        const float r0 = p0 + lane_swap(p0) + 2.f * ur0;
        const float r1 = p1 + lane_swap(p1) + 2.f * ur1;
        const float r2 = p2 + lane_swap(p2);

        // ---- x = Minv r (duplicated on both lanes) ----
        x0 = fmaf(i00, r0, fmaf(i01, r1, i02 * r2));
        x1 = fmaf(i01, r0, fmaf(i11, r1, i12 * r2));
        x2 = fmaf(i02, r0, fmaf(i12, r1, i22 * r2));

        // ---- w' = A x + max(w-b, 0) ----
        const v2 X0 = {x0, x0}, X1 = {x1, x1}, NX2 = {-x2, -x2};
        #pragma unroll
        for (int q = 0; q < 4; ++q) {
            const v2 vv = vfma(ga2[q], X0, vfma(gw2[q], X1, NX2));
            w2[q] = vv + vmax(dobs[q], Z);
        }
        #pragma unroll
        for (int q = 0; q < 2; ++q) {
            const v2 va_ = vfma(gaa2[q], X0, gwa2[q] * X1);
            wav2[q] = va_ + vmax(dav[q], Z);
            wcn2[q] = vmax(dcn[q], Z) - va_;
        }
        const float xsel = hf ? x1 : x0;
        const v2 sx = {-xsel, xsel};
        wbp = sx + vmax(db, Z);
        wb4 = -x2 + fmaxf(wb4, 0.f);
    }

    if (hf == 0)
        reinterpret_cast<float2*>(out)[e] = make_float2(x0, x1);
}

extern "C" void kernel_launch(void* const* d_in, const int* in_sizes, int n_in,
                              void* d_out, int out_size, void* d_ws, size_t ws_size,
                              hipStream_t stream) {
    const float* u_nom  = (const float*)d_in[0];
    const float* v_cur  = (const float*)d_in[1];
    const float* p_obs  = (const float*)d_in[2];
    const float* p_ag   = (const float*)d_in[3];
    const float* v_ag   = (const float*)d_in[4];
    const float* ag_act = (const float*)d_in[5];
    const float* ob_act = (const float*)d_in[6];
    float* out = (float*)d_out;

    const int B = in_sizes[1];            // v_current is (B,1)
    const int threads = 2 * B;
    dim3 block(256), grid((threads + 255) / 256);
    hipLaunchKernelGGL(cbf_admm_kernel, grid, block, 0, stream,
                       u_nom, v_cur, p_obs, p_ag, v_ag, ag_act, ob_act, out, B);
}

// Round 4
// 43.564 us; speedup vs baseline: 1.5335x; 1.1368x over previous
//
#include <hip/hip_runtime.h>

// DifferentiableCBFLayer: batched HOCBF-QP via ADMM (100 iters), 1 thread = 1 elem.
// d-space ADMM (rho=1), state d = w - b per constraint row:
//   t   = b - |d|                      (z - y)
//   r   = -q + A^T t = s - Sum A_k|d_k|,  s = -q + A^T b  (precomputed)
//   x   = Minv r
//   d'  = A_k x - b_k + max(d,0),  max(d,0) = 0.5d + 0.5|d|  (pure pk_fma chain)
// init d0 = min(0,b) - b = min(0,-b).

constexpr int NITERS = 100;

typedef float v2 __attribute__((ext_vector_type(2)));

static __device__ __forceinline__ v2 vfma(v2 a, v2 b, v2 c) { return __builtin_elementwise_fma(a, b, c); }
static __device__ __forceinline__ v2 vmin(v2 a, v2 b)       { return __builtin_elementwise_min(a, b); }
static __device__ __forceinline__ v2 vabs(v2 a)             { return __builtin_elementwise_abs(a); }

__global__ __launch_bounds__(256, 1)
void cbf_admm_kernel(const float* __restrict__ u_nom,   // (B,2)
                     const float* __restrict__ v_cur,   // (B,1)
                     const float* __restrict__ p_obs,   // (B,16,2)
                     const float* __restrict__ p_ag,    // (B,8,2)
                     const float* __restrict__ v_ag,    // (B,8,2)
                     const float* __restrict__ ag_act,  // (B,8)
                     const float* __restrict__ ob_act,  // (B,16)
                     float* __restrict__ out,           // (B,2)
                     int B)
{
    const int b = blockIdx.x * blockDim.x + threadIdx.x;
    if (b >= B) return;

    const float v   = v_cur[b];
    const float2 un = *reinterpret_cast<const float2*>(u_nom + 2 * (size_t)b);

    const v2 Z    = {0.f, 0.f};
    const v2 HALF = {0.5f, 0.5f};

    // ---------------- build obstacle rows (2 per v2) ----------------
    v2 ga2[8], gw2[8], bo2[8];
    v2 sa0 = Z, sa1 = Z, sa2 = Z;     // packed accumulators for s = A^T b
    {
        const float4* po = reinterpret_cast<const float4*>(p_obs + (size_t)b * 32);
        const float2* oa = reinterpret_cast<const float2*>(ob_act + (size_t)b * 16);
        #pragma unroll
        for (int q = 0; q < 8; ++q) {
            const float4 p  = po[q];
            const float2 ac = oa[q];
            const v2 lx = {p.x, p.z};
            const v2 ly = {p.y, p.w};
            const v2 act = {ac.x, ac.y};
            ga2[q] = 2.f * lx;
            gw2[q] = (2.f * v) * ly;
            const v2 h_obs = lx * lx + ly * ly - 0.25f;          // D_OBS^2
            const v2 hdot  = (-2.f * v) * lx;
            const v2 bb = (2.f * v * v + 2.f * hdot + h_obs) * act;  // DAMPING=2, STIFF=1
            bo2[q] = bb;
            sa0 = vfma(ga2[q], bb, sa0);
            sa1 = vfma(gw2[q], bb, sa1);
            sa2 = sa2 + bb;                                      // col2 = -1 -> s2 = -sum(b)
        }
    }

    // ---------------- build agent rows (2 per v2) ----------------
    v2 gaa2[4], gwa2[4], ba2[4], bc2[4];
    {
        const float4* pa = reinterpret_cast<const float4*>(p_ag  + (size_t)b * 16);
        const float4* va = reinterpret_cast<const float4*>(v_ag  + (size_t)b * 16);
        const float2* aa = reinterpret_cast<const float2*>(ag_act + (size_t)b * 8);
        #pragma unroll
        for (int q = 0; q < 4; ++q) {
            const float4 p  = pa[q];
            const float4 w4 = va[q];
            const float2 ac = aa[q];
            const v2 lx = {p.x,  p.z},  ly = {p.y,  p.w};
            const v2 vx = {w4.x, w4.z}, vy = {w4.y, w4.w};
            const v2 act = {ac.x, ac.y};
            const v2 d2  = lx * lx + ly * ly;
            const v2 hdot = (-2.f * v) * lx + 2.f * (lx * vx + ly * vy);
            const v2 hddc = (2.f * v * v) + (-4.f * v) * vx + 2.f * (vx * vx + vy * vy);
            gaa2[q] = (2.f * lx) * act;
            gwa2[q] = ((2.f * v) * ly - 2.f * ly * vx + 2.f * lx * vy) * act;
            const v2 ba = (hddc + 2.f * hdot + (d2 - 0.25f)) * act;   // avoid
            const v2 bc = (-hddc - 2.f * hdot + (100.f - d2)) * act;  // conn
            ba2[q] = ba;
            bc2[q] = bc;
            const v2 dba = ba - bc;
            sa0 = vfma(gaa2[q], dba, sa0);
            sa1 = vfma(gwa2[q], dba, sa1);
        }
    }
    // s vector (box-row constants cancel; -q = +2*u_ref)
    const float s0 = 2.f * un.x + sa0.x + sa0.y;
    const float s1 = 2.f * un.y + sa1.x + sa1.y;
    const float s2 = -(sa2.x + sa2.y);

    // ---------------- M = Q + A^T A (symmetric), closed-form inverse ----------------
    v2 m00 = Z, m01 = Z, m11 = Z, m02 = Z, m12 = Z;
    #pragma unroll
    for (int q = 0; q < 8; ++q) {
        m00 = vfma(ga2[q], ga2[q], m00);
        m01 = vfma(ga2[q], gw2[q], m01);
        m11 = vfma(gw2[q], gw2[q], m11);
        m02 = m02 - ga2[q];
        m12 = m12 - gw2[q];
    }
    #pragma unroll
    for (int q = 0; q < 4; ++q) {   // avoid + conn contribute twice
        const v2 g2 = gaa2[q] + gaa2[q];
        m00 = vfma(g2, gaa2[q], m00);
        m01 = vfma(g2, gwa2[q], m01);
        m11 = vfma(gwa2[q] + gwa2[q], gwa2[q], m11);
    }
    const float M00 = m00.x + m00.y + 4.f;   // Q(2) + box x0 rows(2)
    const float M01 = m01.x + m01.y;
    const float M11 = m11.x + m11.y + 4.f;
    const float M02 = m02.x + m02.y;
    const float M12 = m12.x + m12.y;
    const float M22 = 217.f;                 // 2*W_SLACK + 16 obs rows + slack box row
    const float c00 = M11 * M22 - M12 * M12;
    const float c01 = M02 * M12 - M01 * M22;
    const float c02 = M01 * M12 - M02 * M11;
    const float det = M00 * c00 + M01 * c01 + M02 * c02;
    const float id  = 1.f / det;
    const float i00 = c00 * id, i01 = c01 * id, i02 = c02 * id;
    const float i11 = (M00 * M22 - M02 * M02) * id;
    const float i12 = (M01 * M02 - M00 * M12) * id;
    const float i22 = (M00 * M11 - M01 * M01) * id;

    // ---------------- init d = min(0, -b) ----------------
    v2 do2[8], da2[4], dc2[4];
    #pragma unroll
    for (int q = 0; q < 8; ++q) do2[q] = vmin(Z, -bo2[q]);
    #pragma unroll
    for (int q = 0; q < 4; ++q) { da2[q] = vmin(Z, -ba2[q]); dc2[q] = vmin(Z, -bc2[q]); }
    float db0 = -1.f, db1 = -1.f, db2 = -1.f, db3 = -1.f, d4 = 0.f;  // box b={1,1,1,1,0}

    float x0 = 0.f, x1 = 0.f, x2 = 0.f;

    #pragma unroll 1
    for (int it = 0; it < NITERS; ++it) {
        // ---- reduce: ACC = Sum A_k |d_k| (shared accumulators, all pk_fma) ----
        v2 A0 = Z, A1 = Z, AT = Z;
        v2 ado[8], ada[4], adc[4];
        #pragma unroll
        for (int q = 0; q < 8; ++q) {
            const v2 ad = vabs(do2[q]);
            ado[q] = ad;
            A0 = vfma(ga2[q], ad, A0);
            A1 = vfma(gw2[q], ad, A1);
            AT = AT + ad;                       // obs col2 = -1 -> r2 += |d|
        }
        #pragma unroll
        for (int q = 0; q < 4; ++q) {
            const v2 aa = vabs(da2[q]);  ada[q] = aa;
            const v2 cc = vabs(dc2[q]);  adc[q] = cc;
            const v2 diff = aa - cc;            // conn row = -avoid row
            A0 = vfma(gaa2[q], diff, A0);
            A1 = vfma(gwa2[q], diff, A1);
        }
        // ---- assemble r (box terms: abs modifiers are free on scalar VOP3) ----
        const float rb0 = fabsf(db0) - fabsf(db1);
        const float rb1 = fabsf(db2) - fabsf(db3);
        const float r0 = (s0 + rb0) - (A0.x + A0.y);
        const float r1 = (s1 + rb1) - (A1.x + A1.y);
        const float r2 = (s2 + fabsf(d4)) + (AT.x + AT.y);

        // ---- x = Minv r ----
        x0 = fmaf(i00, r0, fmaf(i01, r1, i02 * r2));
        x1 = fmaf(i01, r0, fmaf(i11, r1, i12 * r2));
        x2 = fmaf(i02, r0, fmaf(i12, r1, i22 * r2));

        // ---- updates: d' = A_k x - b_k + 0.5 d + 0.5 |d| ----
        const v2 X0 = {x0, x0}, X1 = {x1, x1};
        const float nx2 = -x2;
        const v2 MX2 = {nx2, nx2};
        #pragma unroll
        for (int q = 0; q < 8; ++q) {
            v2 u = vfma(HALF, do2[q], MX2 - bo2[q]);
            u = vfma(HALF, ado[q], u);
            u = vfma(gw2[q], X1, u);
            do2[q] = vfma(ga2[q], X0, u);
        }
        #pragma unroll
        for (int q = 0; q < 4; ++q) {
            const v2 va_ = vfma(gaa2[q], X0, gwa2[q] * X1);
            v2 u = vfma(HALF, da2[q], va_);
            u = vfma(HALF, ada[q], u);
            da2[q] = u - ba2[q];
            v2 w = vfma(HALF, dc2[q], -va_);
            w = vfma(HALF, adc[q], w);
            dc2[q] = w - bc2[q];
        }
        db0 = (fmaxf(db0, 0.f) - x0) - 1.f;
        db1 = (fmaxf(db1, 0.f) + x0) - 1.f;
        db2 = (fmaxf(db2, 0.f) - x1) - 1.f;
        db3 = (fmaxf(db3, 0.f) + x1) - 1.f;
        d4  = fmaxf(d4, 0.f) - x2;
    }

    reinterpret_cast<float2*>(out)[b] = make_float2(x0, x1);
}

extern "C" void kernel_launch(void* const* d_in, const int* in_sizes, int n_in,
                              void* d_out, int out_size, void* d_ws, size_t ws_size,
                              hipStream_t stream) {
    const float* u_nom  = (const float*)d_in[0];
    const float* v_cur  = (const float*)d_in[1];
    const float* p_obs  = (const float*)d_in[2];
    const float* p_ag   = (const float*)d_in[3];
    const float* v_ag   = (const float*)d_in[4];
    const float* ag_act = (const float*)d_in[5];
    const float* ob_act = (const float*)d_in[6];
    float* out = (float*)d_out;

    const int B = in_sizes[1];            // v_current is (B,1)
    dim3 block(256), grid((B + 255) / 256);
    hipLaunchKernelGGL(cbf_admm_kernel, grid, block, 0, stream,
                       u_nom, v_cur, p_obs, p_ag, v_ag, ag_act, ob_act, out, B);
}

// Round 5
// 43.065 us; speedup vs baseline: 1.5513x; 1.0116x over previous
//
#include <hip/hip_runtime.h>

// DifferentiableCBFLayer: batched HOCBF-QP via ADMM (100 iters), 1 thread = 1 elem.
// d-space ADMM (rho=1), state d = w - b per constraint row:
//   t   = b - |d|
//   r   = s - Sum A_k|d_k|,  s = -q + A^T b  (precomputed; box consts cancel)
//   x   = Minv r
//   d'  = A_k x - b_k + max(d,0),  max(d,0) = 0.5d + 0.5|d|
// Inner loop forced to VOP3P packed fp32 via inline asm (v_pk_fma/add_f32).

constexpr int NITERS = 100;

typedef float v2 __attribute__((ext_vector_type(2)));

// ---- guaranteed-packed fp32 ops (gfx90a-lineage VOP3P) ----
static __device__ __forceinline__ v2 pk_fma(v2 a, v2 b, v2 c) {          // a*b + c
    v2 d; asm("v_pk_fma_f32 %0, %1, %2, %3" : "=v"(d) : "v"(a), "v"(b), "v"(c)); return d;
}
static __device__ __forceinline__ v2 pk_fma_nc(v2 a, v2 b, v2 c) {       // a*b - c
    v2 d; asm("v_pk_fma_f32 %0, %1, %2, %3 neg_lo:[0,0,1] neg_hi:[0,0,1]"
              : "=v"(d) : "v"(a), "v"(b), "v"(c)); return d;
}
static __device__ __forceinline__ v2 pk_add(v2 a, v2 b) {                // a + b
    v2 d; asm("v_pk_add_f32 %0, %1, %2" : "=v"(d) : "v"(a), "v"(b)); return d;
}
static __device__ __forceinline__ v2 pk_sub(v2 a, v2 b) {                // a - b
    v2 d; asm("v_pk_add_f32 %0, %1, %2 neg_lo:[0,1] neg_hi:[0,1]"
              : "=v"(d) : "v"(a), "v"(b)); return d;
}
static __device__ __forceinline__ v2 pk_mul(v2 a, v2 b) {                // a * b
    v2 d; asm("v_pk_mul_f32 %0, %1, %2" : "=v"(d) : "v"(a), "v"(b)); return d;
}
static __device__ __forceinline__ v2 v2abs(v2 a) { return __builtin_elementwise_abs(a); } // 2x v_and
static __device__ __forceinline__ v2 vfma_(v2 a, v2 b, v2 c) { return __builtin_elementwise_fma(a, b, c); }
static __device__ __forceinline__ v2 vmin_(v2 a, v2 b)       { return __builtin_elementwise_min(a, b); }

__global__ __launch_bounds__(256, 1)
void cbf_admm_kernel(const float* __restrict__ u_nom,   // (B,2)
                     const float* __restrict__ v_cur,   // (B,1)
                     const float* __restrict__ p_obs,   // (B,16,2)
                     const float* __restrict__ p_ag,    // (B,8,2)
                     const float* __restrict__ v_ag,    // (B,8,2)
                     const float* __restrict__ ag_act,  // (B,8)
                     const float* __restrict__ ob_act,  // (B,16)
                     float* __restrict__ out,           // (B,2)
                     int B)
{
    const int b = blockIdx.x * blockDim.x + threadIdx.x;
    if (b >= B) return;

    const float v   = v_cur[b];
    const float2 un = *reinterpret_cast<const float2*>(u_nom + 2 * (size_t)b);

    const v2 Z    = {0.f, 0.f};
    const v2 HALF = {0.5f, 0.5f};

    // ---------------- build obstacle rows (2 per v2) ----------------
    v2 ga2[8], gw2[8], bo2[8];
    v2 sa0 = Z, sa1 = Z, sa2 = Z;
    {
        const float4* po = reinterpret_cast<const float4*>(p_obs + (size_t)b * 32);
        const float2* oa = reinterpret_cast<const float2*>(ob_act + (size_t)b * 16);
        #pragma unroll
        for (int q = 0; q < 8; ++q) {
            const float4 p  = po[q];
            const float2 ac = oa[q];
            const v2 lx = {p.x, p.z};
            const v2 ly = {p.y, p.w};
            const v2 act = {ac.x, ac.y};
            ga2[q] = 2.f * lx;
            gw2[q] = (2.f * v) * ly;
            const v2 h_obs = lx * lx + ly * ly - 0.25f;              // D_OBS^2
            const v2 hdot  = (-2.f * v) * lx;
            const v2 bb = (2.f * v * v + 2.f * hdot + h_obs) * act;  // DAMPING=2, STIFF=1
            bo2[q] = bb;
            sa0 = vfma_(ga2[q], bb, sa0);
            sa1 = vfma_(gw2[q], bb, sa1);
            sa2 = sa2 + bb;
        }
    }

    // ---------------- build agent rows (2 per v2) ----------------
    v2 gaa2[4], gwa2[4], ba2[4], bc2[4];
    {
        const float4* pa = reinterpret_cast<const float4*>(p_ag  + (size_t)b * 16);
        const float4* va = reinterpret_cast<const float4*>(v_ag  + (size_t)b * 16);
        const float2* aa = reinterpret_cast<const float2*>(ag_act + (size_t)b * 8);
        #pragma unroll
        for (int q = 0; q < 4; ++q) {
            const float4 p  = pa[q];
            const float4 w4 = va[q];
            const float2 ac = aa[q];
            const v2 lx = {p.x,  p.z},  ly = {p.y,  p.w};
            const v2 vx = {w4.x, w4.z}, vy = {w4.y, w4.w};
            const v2 act = {ac.x, ac.y};
            const v2 d2  = lx * lx + ly * ly;
            const v2 hdot = (-2.f * v) * lx + 2.f * (lx * vx + ly * vy);
            const v2 hddc = (2.f * v * v) + (-4.f * v) * vx + 2.f * (vx * vx + vy * vy);
            gaa2[q] = (2.f * lx) * act;
            gwa2[q] = ((2.f * v) * ly - 2.f * ly * vx + 2.f * lx * vy) * act;
            const v2 ba = (hddc + 2.f * hdot + (d2 - 0.25f)) * act;   // avoid
            const v2 bc = (-hddc - 2.f * hdot + (100.f - d2)) * act;  // conn
            ba2[q] = ba;
            bc2[q] = bc;
            const v2 dba = ba - bc;
            sa0 = vfma_(gaa2[q], dba, sa0);
            sa1 = vfma_(gwa2[q], dba, sa1);
        }
    }
    const float s0 = 2.f * un.x + sa0.x + sa0.y;
    const float s1 = 2.f * un.y + sa1.x + sa1.y;
    const float s2 = -(sa2.x + sa2.y);

    // ---------------- M = Q + A^T A, closed-form inverse ----------------
    v2 m00 = Z, m01 = Z, m11 = Z, m02 = Z, m12 = Z;
    #pragma unroll
    for (int q = 0; q < 8; ++q) {
        m00 = vfma_(ga2[q], ga2[q], m00);
        m01 = vfma_(ga2[q], gw2[q], m01);
        m11 = vfma_(gw2[q], gw2[q], m11);
        m02 = m02 - ga2[q];
        m12 = m12 - gw2[q];
    }
    #pragma unroll
    for (int q = 0; q < 4; ++q) {
        const v2 g2 = gaa2[q] + gaa2[q];
        m00 = vfma_(g2, gaa2[q], m00);
        m01 = vfma_(g2, gwa2[q], m01);
        m11 = vfma_(gwa2[q] + gwa2[q], gwa2[q], m11);
    }
    const float M00 = m00.x + m00.y + 4.f;
    const float M01 = m01.x + m01.y;
    const float M11 = m11.x + m11.y + 4.f;
    const float M02 = m02.x + m02.y;
    const float M12 = m12.x + m12.y;
    const float M22 = 217.f;
    const float c00 = M11 * M22 - M12 * M12;
    const float c01 = M02 * M12 - M01 * M22;
    const float c02 = M01 * M12 - M02 * M11;
    const float det = M00 * c00 + M01 * c01 + M02 * c02;
    const float id  = 1.f / det;
    const float i00 = c00 * id, i01 = c01 * id, i02 = c02 * id;
    const float i11 = (M00 * M22 - M02 * M02) * id;
    const float i12 = (M01 * M02 - M00 * M12) * id;
    const float i22 = (M00 * M11 - M01 * M01) * id;

    // ---------------- init d = min(0, -b) ----------------
    v2 do2[8], da2[4], dc2[4];
    #pragma unroll
    for (int q = 0; q < 8; ++q) do2[q] = vmin_(Z, -bo2[q]);
    #pragma unroll
    for (int q = 0; q < 4; ++q) { da2[q] = vmin_(Z, -ba2[q]); dc2[q] = vmin_(Z, -bc2[q]); }
    float db0 = -1.f, db1 = -1.f, db2 = -1.f, db3 = -1.f, d4 = 0.f;

    float x0 = 0.f, x1 = 0.f, x2 = 0.f;

    #pragma unroll 1
    for (int it = 0; it < NITERS; ++it) {
        // ---- reduce: ACC = Sum A_k |d_k| ----
        v2 A0 = Z, A1 = Z, AT = Z;
        v2 ado[8], ada[4], adc[4];
        #pragma unroll
        for (int q = 0; q < 8; ++q) {
            const v2 ad = v2abs(do2[q]);
            ado[q] = ad;
            A0 = pk_fma(ga2[q], ad, A0);
            A1 = pk_fma(gw2[q], ad, A1);
            AT = pk_add(AT, ad);
        }
        #pragma unroll
        for (int q = 0; q < 4; ++q) {
            const v2 aa = v2abs(da2[q]);  ada[q] = aa;
            const v2 cc = v2abs(dc2[q]);  adc[q] = cc;
            const v2 diff = pk_sub(aa, cc);
            A0 = pk_fma(gaa2[q], diff, A0);
            A1 = pk_fma(gwa2[q], diff, A1);
        }
        const float rb0 = fabsf(db0) - fabsf(db1);
        const float rb1 = fabsf(db2) - fabsf(db3);
        const float r0 = (s0 + rb0) - (A0.x + A0.y);
        const float r1 = (s1 + rb1) - (A1.x + A1.y);
        const float r2 = (s2 + fabsf(d4)) + (AT.x + AT.y);

        // ---- x = Minv r ----
        x0 = fmaf(i00, r0, fmaf(i01, r1, i02 * r2));
        x1 = fmaf(i01, r0, fmaf(i11, r1, i12 * r2));
        x2 = fmaf(i02, r0, fmaf(i12, r1, i22 * r2));

        // ---- updates: d' = A_k x - b_k + 0.5 d + 0.5 |d| ----
        const v2 X0 = {x0, x0}, X1 = {x1, x1};
        const float nx2 = -x2;
        const v2 MX2 = {nx2, nx2};
        #pragma unroll
        for (int q = 0; q < 8; ++q) {
            v2 u = pk_fma(HALF, do2[q], pk_sub(MX2, bo2[q]));
            u = pk_fma(HALF, ado[q], u);
            u = pk_fma(gw2[q], X1, u);
            do2[q] = pk_fma(ga2[q], X0, u);
        }
        #pragma unroll
        for (int q = 0; q < 4; ++q) {
            const v2 va_ = pk_fma(gaa2[q], X0, pk_mul(gwa2[q], X1));
            // avoid: da' = va - ba + 0.5 da + 0.5 |da|
            v2 u = pk_fma(HALF, da2[q], pk_sub(va_, ba2[q]));
            da2[q] = pk_fma(HALF, ada[q], u);
            // conn: dc' = -va - bc + 0.5 dc + 0.5 |dc|
            v2 w = pk_fma_nc(HALF, dc2[q], pk_add(va_, bc2[q]));
            dc2[q] = pk_fma(HALF, adc[q], w);
        }
        const float c0m = -x0 - 1.f, c0p = x0 - 1.f;
        const float c1m = -x1 - 1.f, c1p = x1 - 1.f;
        db0 = fmaxf(db0, 0.f) + c0m;
        db1 = fmaxf(db1, 0.f) + c0p;
        db2 = fmaxf(db2, 0.f) + c1m;
        db3 = fmaxf(db3, 0.f) + c1p;
        d4  = fmaxf(d4, 0.f) - x2;
    }

    reinterpret_cast<float2*>(out)[b] = make_float2(x0, x1);
}

extern "C" void kernel_launch(void* const* d_in, const int* in_sizes, int n_in,
                              void* d_out, int out_size, void* d_ws, size_t ws_size,
                              hipStream_t stream) {
    const float* u_nom  = (const float*)d_in[0];
    const float* v_cur  = (const float*)d_in[1];
    const float* p_obs  = (const float*)d_in[2];
    const float* p_ag   = (const float*)d_in[3];
    const float* v_ag   = (const float*)d_in[4];
    const float* ag_act = (const float*)d_in[5];
    const float* ob_act = (const float*)d_in[6];
    float* out = (float*)d_out;

    const int B = in_sizes[1];            // v_current is (B,1)
    dim3 block(256), grid((B + 255) / 256);
    hipLaunchKernelGGL(cbf_admm_kernel, grid, block, 0, stream,
                       u_nom, v_cur, p_obs, p_ag, v_ag, ag_act, ob_act, out, B);
}